// Round 13
// baseline (36.814 us; speedup 1.0000x reference)
//
#include <hip/hip_runtime.h>

typedef unsigned long long ull;
#define NT 100

// Lock-free min-root union-find in LDS. Parent strictly decreases along
// chains -> termination, no cycles.
__device__ __forceinline__ int find_root(int* P, int x) {
    int p = P[x];
    while (p != x) {
        int gp = P[p];
        P[x] = gp;          // benign racy path-halving (gp is an ancestor, gp < x)
        x = gp;
        p = P[x];
    }
    return x;
}

// Returns 1 iff this call performed the hook (merged two distinct trees).
// Per-BLOCK total of successful hooks == components merged: schedule-
// invariant, so the block-combined value is deterministic.
__device__ __forceinline__ int unite(int* P, int a, int b) {
    a = find_root(P, a);
    b = find_root(P, b);
    while (a != b) {
        if (a < b) { int t = a; a = b; b = t; }   // hook larger under smaller
        int old = atomicCAS(&P[a], a, b);
        if (old == a) return 1;
        a = find_root(P, old);
        b = find_root(P, b);
    }
    return 0;
}

// ws layout: partials ws[0..6399] (tile*4+h), counters ws[6400 + b*8]
// (64B-padded). Counters are NEVER initialized: garbage-start-safe via
// mod-200 test (exactly one of G+1..G+200 is ==0 mod 200 per call).
//
// One 256-thread block per (b,c,t) tile. XCD swizzle: dispatch d -> XCD d%8;
// tile = (d&7)*200 + (d>>3) gives XCD x the range [x*200,x*200+200) =
// image b=x -> image reads, ws partials, counter[b] all XCD-local.
// The block whose counter increment hits %200==0 (the last of its image)
// inlines the finisher: combines 200 tiles' partials, stores out[b].
__global__ __launch_bounds__(256)
void betti_lastblock(const float* __restrict__ prob,   // [8,3,64,64]
                     const int*  __restrict__ gt,      // [8,3,100,2]
                     ull* __restrict__ ws,
                     float* __restrict__ out)          // [8]
{
    __shared__ int P[2048];
    __shared__ int bL[3][64];                 // run id at col 16h+15, or -1
    __shared__ int bR[3][64];                 // run id at col 16(h+1), or -1
    __shared__ int wsum[4];
    __shared__ int amFin;

    const int d    = blockIdx.x;
    const int tile = (d & 7) * 200 + (d >> 3);   // (b*2 + c)*100 + t
    const int t    = tile % NT;
    const int cb   = tile / NT;
    const int b    = cb >> 1;

    const float thr = (float)t * (1.0f / 99.0f);
    const float* img = prob + (size_t)(b * 3 + (cb & 1)) * 4096;

    const int tid  = threadIdx.x;
    const int h    = tid >> 6;                // wave = column quarter
    const int lane = tid & 63;                // row

    // ---- load row `lane`, cols 16h..16h+15 (4 x float4), build 16-bit mask ----
    const float4* rp = (const float4*)(img + (lane << 6) + (h << 4));
    unsigned int m = 0;
    #pragma unroll
    for (int q = 0; q < 4; ++q) {
        float4 v = rp[q];
        m |= (unsigned)(v.x > thr) << (4 * q + 0);
        m |= (unsigned)(v.y > thr) << (4 * q + 1);
        m |= (unsigned)(v.z > thr) << (4 * q + 2);
        m |= (unsigned)(v.w > thr) << (4 * q + 3);
    }

    // ---- init my 8 UF slots (only my wave touches them pre-barrier) ----
    #pragma unroll
    for (int k = 0; k < 8; ++k) {
        int s = ((h * 8 + k) << 6) | lane;
        P[s] = s;
    }

    const unsigned um = m & 0xFFFFu;
    unsigned up        = (unsigned)__shfl_up((int)um, 1, 64);
    unsigned starts    = um & ~(um << 1) & 0xFFFFu;       // run starts
    unsigned starts_up = (unsigned)__shfl_up((int)starts, 1, 64);
    if (lane == 0) { up = 0u; starts_up = 0u; }

    const int px    = __popc(um);
    int       eh    = __popc(um & (um >> 1));             // horiz edges in quarter
    const int ev    = __popc(um & up);                    // vert edges in quarter
    const int nruns = __popc(starts);

    // ---- boundary descriptors (written pre-barrier, read post-barrier) ----
    if (h < 3)   // run containing col15 is the last-starting run: index nruns-1
        bL[h][lane] = ((um >> 15) & 1u) ? (((h * 8 + (nruns - 1)) << 6) | lane) : -1;
    if (h > 0)   // if col 16h is set, it is a run start: index 0
        bR[h - 1][lane] = (um & 1u) ? (((h * 8) << 6) | lane) : -1;

    // ---- within-quarter vertical-overlap unions (own slots only) ----
    int merges = 0;
    unsigned ov = um & up;
    unsigned ss = ov & ~(ov << 1) & 0xFFFFu;              // segment starts
    while (ss) {
        int j = __ffs(ss) - 1;
        ss &= ss - 1;
        unsigned le = (2u << j) - 1;                      // bits [0..j]
        int kc = __popc(starts    & le) - 1;
        int ku = __popc(starts_up & le) - 1;
        merges += unite(P, ((h * 8 + kc) << 6) | lane, ((h * 8 + ku) << 6) | (lane - 1));
    }

    __syncthreads();   // all inits + bL/bR + (disjoint) within-unions visible

    // ---- boundary unions + crossing horizontal edges (waves 0..2) ----
    if (h < 3) {
        int l = bL[h][lane], r = bR[h][lane];
        if (l >= 0 && r >= 0) { eh++; merges += unite(P, l, r); }
    }

    // ---- packed {px(13)|eh(12)|ev(12)|nruns(12)|merges(12)} wave reduce ----
    // block totals: px<=4096, eh<=4032, ev<=4032, nruns<=2048, merges<2048
    ull pk = (ull)px
           | ((ull)eh     << 13)
           | ((ull)ev     << 25)
           | ((ull)nruns  << 37)
           | ((ull)merges << 49);
    #pragma unroll
    for (int o = 32; o > 0; o >>= 1)
        pk += __shfl_down(pk, o, 64);

    if (lane == 0) ws[(size_t)tile * 4 + h] = pk;         // plain store

    // ---- last-block election (no spin, no memset) ----
    __syncthreads();   // all 4 ws stores issued before the release below
    if (tid == 0) {
        // acq_rel: release makes this block's ws stores (happens-before via
        // barrier) agent-visible; acquire synchronizes with the other 199
        // releases when we are last.
        ull newv = __hip_atomic_fetch_add(&ws[6400 + (size_t)b * 8], 1ull,
                                          __ATOMIC_ACQ_REL,
                                          __HIP_MEMORY_SCOPE_AGENT) + 1ull;
        amFin = (newv % 200ull == 0ull) ? 1 : 0;
    }
    __syncthreads();
    if (!amFin) return;

    // ---------------- finisher: combine image b, store out[b] ----------------
    int contrib = 0;
    if (tid < 200) {                                      // tid = c*100 + tt
        const ull* p = ws + (size_t)(b * 200 + tid) * 4;
        ull s = p[0] + p[1] + p[2] + p[3];
        const int spx = (int)( s        & 0x1FFF);
        const int seh = (int)((s >> 13) & 0xFFF);
        const int sev = (int)((s >> 25) & 0xFFF);
        const int nr  = (int)((s >> 37) & 0xFFF);
        const int mg  = (int)((s >> 49) & 0xFFF);
        const int b0  = nr - mg;
        const int b1  = b0 - (spx - (seh + sev));

        const int c  = tid / 100;
        const int tt = tid - c * 100;
        int dd;
        if (c == 0) {
            const int* g0 = gt + (((size_t)b * 3 + 0) * NT + tt) * 2;
            const int* g2 = gt + (((size_t)b * 3 + 2) * NT + tt) * 2;
            dd = b0 - g0[0]; contrib += dd < 0 ? -dd : dd;
            dd = b1 - g0[1]; contrib += dd < 0 ? -dd : dd;
            dd = b0 - g2[0]; contrib += dd < 0 ? -dd : dd;
            dd = b1 - g2[1]; contrib += dd < 0 ? -dd : dd;
        } else {
            const int* g1 = gt + (((size_t)b * 3 + 1) * NT + tt) * 2;
            dd = b0 - g1[0]; contrib += dd < 0 ? -dd : dd;
            dd = b1 - g1[1]; contrib += dd < 0 ? -dd : dd;
        }
    }

    #pragma unroll
    for (int o = 32; o > 0; o >>= 1) contrib += __shfl_down(contrib, o, 64);
    if ((tid & 63) == 0) wsum[tid >> 6] = contrib;
    __syncthreads();
    if (tid == 0)
        out[b] = (float)(wsum[0] + wsum[1] + wsum[2] + wsum[3]);
}

extern "C" void kernel_launch(void* const* d_in, const int* in_sizes, int n_in,
                              void* d_out, int out_size, void* d_ws, size_t ws_size,
                              hipStream_t stream) {
    const float* prob = (const float*)d_in[0];   // [8,3,64,64] f32
    const int*   gt   = (const int*)d_in[1];     // [8,3,100,2] i32
    float* out = (float*)d_out;                  // [8] f32
    ull* ws = (ull*)d_ws;                        // 6400 partials + 8*8 counters

    const int nblocks = 8 * 2 * NT;   // 1600 blocks, one per (b,c,t)
    betti_lastblock<<<nblocks, 256, 0, stream>>>(prob, gt, ws, out);
}